// Round 11
// baseline (276.761 us; speedup 1.0000x reference)
//
#include <hip/hip_runtime.h>
#include <hip/hip_bf16.h>

typedef __attribute__((ext_vector_type(8))) short s16x8;
typedef __attribute__((ext_vector_type(16))) float f32x16;

#define MOD_SCALE 0.014731391274719739f  // 1/sqrt(512*9)

__device__ __forceinline__ void gload_lds16(const void* g, void* l) {
    __builtin_amdgcn_global_load_lds(
        (const __attribute__((address_space(1))) unsigned int*)g,
        (__attribute__((address_space(3))) unsigned int*)l, 16, 0, 0);
}

// Full drain + barrier (proven R7/R12 semantics).
__device__ __forceinline__ void sync_drain() {
    __builtin_amdgcn_s_waitcnt(0);
    __syncthreads();
}

// ---------------------------------------------------------------------------
// xs layout (channel-blocked, proven): [b][cb=16][row=66][col=66][32ci*2B]
//   b stride 4,460,544 B; cb stride 278,784 B; entry stride 64 B.
//
// k_prep (R16 lean version, proven):
//   [0,512) xprep | [512,1032) border | [1032,1288) wprep | [1288,1800) demod
// ---------------------------------------------------------------------------
__global__ __launch_bounds__(256) void k_prep(const float* __restrict__ x,
                                              const float* __restrict__ style,
                                              const float* __restrict__ weight,
                                              __hip_bfloat16* __restrict__ xs,
                                              __hip_bfloat16* __restrict__ wb,
                                              float* __restrict__ dem) {
    __shared__ __align__(16) char sm[36864];
    const int t = threadIdx.x;
    const int bid = blockIdx.x;

    if (bid < 512) {
        // xprep: one block per (b,h); 4 iterations of 128 ci x 64 w
        const int b = bid >> 6, h = bid & 63;
        __hip_bfloat16 (*tile)[68] = (__hip_bfloat16(*)[68])sm;  // 17,408 B
        float* sf = (float*)(sm + 17408);                        // 512 floats
        sf[t] = style[b * 512 + t] * MOD_SCALE;
        sf[t + 256] = style[b * 512 + 256 + t] * MOD_SCALE;
        const float* xb = x + (size_t)b * 512 * 4096 + h * 64;
        const int cig = t & 3, w = t >> 2;
        char* ob = (char*)xs + (size_t)b * 4460544 +
                   (size_t)((h + 1) * 66 + 1) * 64;
        __syncthreads();
#pragma unroll
        for (int cq = 0; cq < 4; ++cq) {
#pragma unroll 4
            for (int it = 0; it < 8; ++it) {
                int idx = it * 256 + t;
                int cil = idx >> 4, w4 = idx & 15;
                int ci = cq * 128 + cil;
                float4 v = *(const float4*)(xb + (size_t)ci * 4096 + w4 * 4);
                float s = sf[ci];
                union { uint2 u2; __hip_bfloat16 q[4]; } pk;
                pk.q[0] = __float2bfloat16(v.x * s);
                pk.q[1] = __float2bfloat16(v.y * s);
                pk.q[2] = __float2bfloat16(v.z * s);
                pk.q[3] = __float2bfloat16(v.w * s);
                *(uint2*)&tile[cil][w4 * 4] = pk.u2;  // 136B row: 8-aligned
            }
            __syncthreads();
#pragma unroll
            for (int cbl = 0; cbl < 4; ++cbl) {
                const int cb = cq * 4 + cbl;
                union { uint4 u; __hip_bfloat16 q[8]; } pk;
#pragma unroll
                for (int j = 0; j < 8; ++j)
                    pk.q[j] = tile[cbl * 32 + cig * 8 + j][w];
                *(uint4*)(ob + (size_t)cb * 278784 + w * 64 + cig * 16) = pk.u;
            }
            __syncthreads();
        }
    } else if (bid < 1032) {
        const int idx = (bid - 512) * 256 + t;
        const int b = idx / 16640;
        const int r2 = idx - b * 16640;
        const int cb = r2 / 1040;
        const int r3 = r2 - cb * 1040;
        const int pair = r3 >> 2;
        const int chunk = r3 & 3;
        int pr, pc;
        if (pair < 66)       { pr = 0;          pc = pair; }
        else if (pair < 132) { pr = 65;         pc = pair - 66; }
        else if (pair < 196) { pr = pair - 131; pc = 0; }
        else                 { pr = pair - 195; pc = 65; }
        char* d = (char*)xs +
                  ((size_t)(b * 16 + cb) * 4356 + pr * 66 + pc) * 64 +
                  chunk * 16;
        *(uint4*)d = make_uint4(0u, 0u, 0u, 0u);
    } else if (bid < 1288) {
        // wprep: 256 blocks x 1024 (co,ci) pairs; uint2 stores (4 bf16)
        const int r = bid - 1032;
        float* lds = (float*)sm;                 // 9216 floats = 36,864 B
        const int p0 = r * 1024;
        const float* src = weight + (size_t)p0 * 9;
#pragma unroll
        for (int k = 0; k < 36; ++k) lds[k * 256 + t] = src[k * 256 + t];
        __syncthreads();
#pragma unroll
        for (int tap = 0; tap < 9; ++tap) {
            union { uint2 u; __hip_bfloat16 q[4]; } pk;
#pragma unroll
            for (int j = 0; j < 4; ++j)
                pk.q[j] = __float2bfloat16(lds[(4 * t + j) * 9 + tap]);
            *(uint2*)(wb + (size_t)tap * 262144 + p0 + 4 * t) = pk.u;
        }
    } else {
        const int co = bid - 1288;
        float* s2 = (float*)sm;
        for (int i = t; i < 4096; i += 256) { float v = style[i]; s2[i] = v * v; }
        __syncthreads();
        const float4* wp = (const float4*)(weight + (size_t)co * 4608);
        float acc[8] = {0.f, 0.f, 0.f, 0.f, 0.f, 0.f, 0.f, 0.f};
        for (int j = t; j < 1152; j += 256) {
            float4 v = wp[j];
            float w2[4] = {v.x * v.x, v.y * v.y, v.z * v.z, v.w * v.w};
            int base = j * 4;
#pragma unroll
            for (int e = 0; e < 4; ++e) {
                int ci = (base + e) / 9;
                float ww = w2[e];
#pragma unroll
                for (int bb = 0; bb < 8; ++bb) acc[bb] += ww * s2[bb * 512 + ci];
            }
        }
#pragma unroll
        for (int bb = 0; bb < 8; ++bb)
            for (int off = 32; off > 0; off >>= 1)
                acc[bb] += __shfl_down(acc[bb], off);
        float* red = (float*)(sm + 16384);
        const int wv = t >> 6, lane = t & 63;
        if (lane == 0) {
#pragma unroll
            for (int bb = 0; bb < 8; ++bb) red[wv * 8 + bb] = acc[bb];
        }
        __syncthreads();
        if (t < 8) {
            float s = red[t] + red[8 + t] + red[16 + t] + red[24 + t];
            const float S2 = MOD_SCALE * MOD_SCALE;
            dem[t * 512 + co] = rsqrtf(S2 * s + 1e-8f);
        }
    }
}

// ---------------------------------------------------------------------------
// Conv R17: SMALL-BLOCK variant — 128co x 128sp (2 output rows), 128 threads
// = 2 waves, each the PROVEN 64co x 128sp wave tile (2x4 frags, 0.75
// ds_read/MFMA). Per-CU totals (MFMA, ds_read) identical to R12, but LDS
// drops to 33,280 B -> FOUR blocks/CU (grid 1024 = exact 4/CU): 4
// independent barrier domains instead of 2. Mechanism: R7-R15 showed the
// read-burst/MFMA-burst alternation is immune to intra-block scheduling;
// inter-block phase drift is the remaining way to overlap one block's LDS
// reads with another's MFMAs. Sync skeleton = R7's proven per-tap W dbuf.
//   Xl: 4 rows x 66 x 64 B = 16,896. Wl: 2 x 8,192. Total 33,280 B.
// ---------------------------------------------------------------------------
__global__ __launch_bounds__(128, 2) void k_conv(
    const __hip_bfloat16* __restrict__ xs,   // [b][16][66][66][64B] blocked
    const __hip_bfloat16* __restrict__ wb,   // [9][512][512] tap-major
    const float* __restrict__ demod,
    const float* __restrict__ noise,
    const float* __restrict__ bias,
    const float* __restrict__ nstr,
    float* __restrict__ out) {
    __shared__ __align__(16) char Xl[16896];     // 264 entries x 64 B
    __shared__ __align__(16) char Wl[2][8192];   // 128 co x 64 B, dbuf

    const int t = threadIdx.x;            // 0..127
    const int bi = blockIdx.x;
    const int spat = bi & 255;            // co-siblings at bi±256: same XCD
    const int b = spat >> 5;
    const int h0 = (spat & 31) << 1;      // 2 output rows per block
    const int co0 = (bi >> 8) << 7;
    const int lane = t & 63;
    const int wv = t >> 6;                // co half (wave index)
    const int el = lane & 31;
    const int hk = lane >> 5;

    f32x16 acc[2][4];                     // [mi][ni]
#pragma unroll
    for (int i = 0; i < 2; ++i)
#pragma unroll
        for (int j = 0; j < 4; ++j)
#pragma unroll
            for (int k = 0; k < 16; ++k) acc[i][j][k] = 0.f;

    // ---- X staging pointers (rotation-swizzled): 1056 units of 16 B ----
    const char* xsb = (const char*)xs + (size_t)b * 4460544;
    const char* xsrc[9];
#pragma unroll
    for (int i = 0; i < 8; ++i) {
        int g = i * 128 + t;
        int e = g >> 2, s = g & 3;
        int gc = (s - (e >> 2)) & 3;
        int row = e / 66, col = e - row * 66;
        xsrc[i] = xsb + (size_t)((h0 + row) * 66 + col) * 64 + gc * 16;
    }
    {   // tail: units 1024..1055 (entries 256..263), threads 0..31 only
        int g = 1024 + t;
        int e = g >> 2, s = g & 3;
        int gc = (s - (e >> 2)) & 3;
        int row = e / 66, col = e - row * 66;
        xsrc[8] = xsb + (size_t)((h0 + row) * 66 + col) * 64 + gc * 16;
    }
    // ---- W staging pointers: 512 units of 16 B per tap-buffer, 4 rounds ----
    const char* wsrc[4];
#pragma unroll
    for (int i = 0; i < 4; ++i) {
        int g = i * 128 + t;
        int e = g >> 2, s = g & 3;
        int gc = (s - (e >> 2)) & 3;
        wsrc[i] = (const char*)wb + (size_t)(co0 + e) * 1024 + gc * 16;
    }
    const int wvoff = wv << 10;           // per-wave 1 KB offset within rounds

    // ---- prologue: X(cb=0) + W(tap0) -> buf0 ----
#pragma unroll
    for (int i = 0; i < 8; ++i) gload_lds16(xsrc[i], Xl + i * 2048 + wvoff);
    if (t < 32) gload_lds16(xsrc[8], Xl + 16384);
#pragma unroll
    for (int i = 0; i < 4; ++i)
        gload_lds16(wsrc[i], Wl[0] + i * 2048 + wvoff);
    sync_drain();

    int cboff = 0;
    for (int cb = 0; cb < 16; ++cb, cboff += 64) {
#pragma unroll
        for (int tap = 0; tap < 9; ++tap) {
            const int buf = (cb + tap) & 1;   // 9 odd -> parity = (cb+tap)&1
            // ---- prefetch next W step into the other buffer ----
            if (tap < 8) {
                char* Wn = Wl[buf ^ 1];
#pragma unroll
                for (int i = 0; i < 4; ++i)
                    gload_lds16(wsrc[i] + (size_t)(tap + 1) * 524288 + cboff,
                                Wn + i * 2048 + wvoff);
            } else if (cb < 15) {
                char* Wn = Wl[buf ^ 1];
#pragma unroll
                for (int i = 0; i < 4; ++i)
                    gload_lds16(wsrc[i] + cboff + 64, Wn + i * 2048 + wvoff);
            }
            // ---- compute tap (dh = tap/3, dw = tap%3) ----
            const int dh = tap / 3, dw = tap % 3;
            const char* Wb = Wl[buf];
#pragma unroll
            for (int ks = 0; ks < 2; ++ks) {
                const int c = 2 * ks + hk;
                s16x8 af[2], bfr[4];
#pragma unroll
                for (int mi = 0; mi < 2; ++mi) {
                    int e = wv * 64 + mi * 32 + el;
                    af[mi] = *(const s16x8*)(Wb + e * 64 +
                                             (((c + (e >> 2)) & 3) << 4));
                }
#pragma unroll
                for (int ni = 0; ni < 4; ++ni) {
                    int e = ((ni >> 1) + dh) * 66 + dw + (ni & 1) * 32 + el;
                    bfr[ni] = *(const s16x8*)(Xl + e * 64 +
                                              (((c + (e >> 2)) & 3) << 4));
                }
#pragma unroll
                for (int mi = 0; mi < 2; ++mi)
#pragma unroll
                    for (int ni = 0; ni < 4; ++ni)
                        acc[mi][ni] = __builtin_amdgcn_mfma_f32_32x32x16_bf16(
                            af[mi], bfr[ni], acc[mi][ni], 0, 0, 0);
            }
            sync_drain();
        }
        // ---- restage X for cb+1 (single buffer, own barrier pair) ----
        if (cb < 15) {
            const size_t xo = (size_t)(cb + 1) * 278784;
#pragma unroll
            for (int i = 0; i < 8; ++i)
                gload_lds16(xsrc[i] + xo, Xl + i * 2048 + wvoff);
            if (t < 32) gload_lds16(xsrc[8] + xo, Xl + 16384);
            sync_drain();
        }
    }

    // ---- epilogue: *demod + noise*strength + bias, leaky_relu(0.2)*sqrt(2) ----
    const float nsv = nstr[0];
    const float LR = 1.4142135623730951f;
#pragma unroll
    for (int mi = 0; mi < 2; ++mi) {
        float dm[16], bs[16];
#pragma unroll
        for (int rg = 0; rg < 16; ++rg) {
            int co = co0 + wv * 64 + mi * 32 + (rg & 3) + 8 * (rg >> 2) + 4 * hk;
            dm[rg] = demod[b * 512 + co];
            bs[rg] = bias[co];
        }
#pragma unroll
        for (int ni = 0; ni < 4; ++ni) {
            int h = h0 + (ni >> 1);
            int w = (ni & 1) * 32 + el;
            float nz = nsv * noise[h * 64 + w];
#pragma unroll
            for (int rg = 0; rg < 16; ++rg) {
                int co = co0 + wv * 64 + mi * 32 + (rg & 3) + 8 * (rg >> 2) +
                         4 * hk;
                float v = acc[mi][ni][rg] * dm[rg] + nz + bs[rg];
                v = (v >= 0.f ? v : 0.2f * v) * LR;
                out[(((size_t)b * 512 + co) * 64 + h) * 64 + w] = v;
            }
        }
    }
}

// ---------------------------------------------------------------------------
extern "C" void kernel_launch(void* const* d_in, const int* in_sizes, int n_in,
                              void* d_out, int out_size, void* d_ws, size_t ws_size,
                              hipStream_t stream) {
    const float* x      = (const float*)d_in[0];
    const float* style  = (const float*)d_in[1];
    const float* noise  = (const float*)d_in[2];
    const float* weight = (const float*)d_in[3];
    const float* bias   = (const float*)d_in[4];
    const float* nstr   = (const float*)d_in[5];
    float* out = (float*)d_out;

    char* ws = (char*)d_ws;
    __hip_bfloat16* xs = (__hip_bfloat16*)ws;              // 35,684,352 B (blocked)
    __hip_bfloat16* wb = (__hip_bfloat16*)(ws + 35684352); //  4,718,592 B
    float* demod = (float*)(ws + 35684352 + 4718592);      //     16,384 B

    k_prep<<<1800, 256, 0, stream>>>(x, style, weight, xs, wb, demod);
    k_conv<<<1024, 128, 0, stream>>>(xs, wb, demod, noise, bias, nstr, out);
}

// Round 12
// 249.494 us; speedup vs baseline: 1.1093x; 1.1093x over previous
//
#include <hip/hip_runtime.h>
#include <hip/hip_bf16.h>

typedef __attribute__((ext_vector_type(8))) short s16x8;
typedef __attribute__((ext_vector_type(16))) float f32x16;

#define MOD_SCALE 0.014731391274719739f  // 1/sqrt(512*9)

__device__ __forceinline__ void gload_lds16(const void* g, void* l) {
    __builtin_amdgcn_global_load_lds(
        (const __attribute__((address_space(1))) unsigned int*)g,
        (__attribute__((address_space(3))) unsigned int*)l, 16, 0, 0);
}

// Full drain + barrier (R9/R12 semantics, proven).
__device__ __forceinline__ void sync_drain() {
    __builtin_amdgcn_s_waitcnt(0);
    __syncthreads();
}

// ---------------------------------------------------------------------------
// xs layout (channel-blocked, proven): [b][cb=16][row=66][col=66][32ci*2B]
//   b stride 4,460,544 B; cb stride 278,784 B; entry stride 64 B.
//
// k_prep (R12 record config): blockIdx ranges (xprep first)
//   [0,512) xprep | [512,1032) border | [1032,2056) wprep | [2056,2568) demod
// xprep: [128][68] tile, 4 ci-quarter iterations; float4 loads, uint4 stores;
// static LDS 19,456 B -> 8 blocks/CU for all sections.
// ---------------------------------------------------------------------------
__global__ __launch_bounds__(256) void k_prep(const float* __restrict__ x,
                                              const float* __restrict__ style,
                                              const float* __restrict__ weight,
                                              __hip_bfloat16* __restrict__ xs,
                                              __hip_bfloat16* __restrict__ wb,
                                              float* __restrict__ dem) {
    __shared__ __align__(16) char sm[19456];  // xprep: 17408 tile + 2048 style
    const int t = threadIdx.x;
    const int bid = blockIdx.x;

    if (bid < 512) {
        // xprep: one block per (b,h); 4 iterations of 128 ci x 64 w
        const int b = bid >> 6, h = bid & 63;
        __hip_bfloat16 (*tile)[68] = (__hip_bfloat16(*)[68])sm;  // 17,408 B
        float* sf = (float*)(sm + 17408);                        // 512 floats
        sf[t] = style[b * 512 + t] * MOD_SCALE;
        sf[t + 256] = style[b * 512 + 256 + t] * MOD_SCALE;
        const float* xb = x + (size_t)b * 512 * 4096 + h * 64;
        const int cig = t & 3, w = t >> 2;
        char* ob = (char*)xs + (size_t)b * 4460544 +
                   (size_t)((h + 1) * 66 + 1) * 64;
        __syncthreads();
#pragma unroll
        for (int cq = 0; cq < 4; ++cq) {
            // load 128 ci x 64 w (float4 = 16B/lane, 256B coalesced per row)
#pragma unroll 4
            for (int it = 0; it < 8; ++it) {
                int idx = it * 256 + t;
                int cil = idx >> 4, w4 = idx & 15;
                int ci = cq * 128 + cil;
                float4 v = *(const float4*)(xb + (size_t)ci * 4096 + w4 * 4);
                float s = sf[ci];
                union { uint2 u2; __hip_bfloat16 q[4]; } pk;
                pk.q[0] = __float2bfloat16(v.x * s);
                pk.q[1] = __float2bfloat16(v.y * s);
                pk.q[2] = __float2bfloat16(v.z * s);
                pk.q[3] = __float2bfloat16(v.w * s);
                *(uint2*)&tile[cil][w4 * 4] = pk.u2;  // 136B row: 8-aligned
            }
            __syncthreads();
            // transpose-gather: rows stride 34 dw -> 2-way bank max (free);
            // one uint4 coalesced store per (cb, thread)
#pragma unroll
            for (int cbl = 0; cbl < 4; ++cbl) {
                const int cb = cq * 4 + cbl;
                union { uint4 u; __hip_bfloat16 q[8]; } pk;
#pragma unroll
                for (int j = 0; j < 8; ++j)
                    pk.q[j] = tile[cbl * 32 + cig * 8 + j][w];
                *(uint4*)(ob + (size_t)cb * 278784 + w * 64 + cig * 16) = pk.u;
            }
            __syncthreads();
        }
    } else if (bid < 1032) {
        // border zero: 8 b x 16 cb x 260 border entries x 4 chunks
        const int idx = (bid - 512) * 256 + t;
        const int b = idx / 16640;
        const int r2 = idx - b * 16640;
        const int cb = r2 / 1040;
        const int r3 = r2 - cb * 1040;
        const int pair = r3 >> 2;
        const int chunk = r3 & 3;
        int pr, pc;
        if (pair < 66)       { pr = 0;          pc = pair; }
        else if (pair < 132) { pr = 65;         pc = pair - 66; }
        else if (pair < 196) { pr = pair - 131; pc = 0; }
        else                 { pr = pair - 195; pc = 65; }
        char* d = (char*)xs +
                  ((size_t)(b * 16 + cb) * 4356 + pr * 66 + pc) * 64 +
                  chunk * 16;
        *(uint4*)d = make_uint4(0u, 0u, 0u, 0u);
    } else if (bid < 2056) {
        const int r = bid - 1032;
        float* lds = (float*)sm;
        const int p0 = r * 256;
        const float* src = weight + (size_t)p0 * 9;
#pragma unroll
        for (int k = 0; k < 9; ++k) lds[k * 256 + t] = src[k * 256 + t];
        __syncthreads();
#pragma unroll
        for (int tap = 0; tap < 9; ++tap)
            wb[(size_t)tap * 262144 + p0 + t] = __float2bfloat16(lds[t * 9 + tap]);
    } else {
        const int co = bid - 2056;
        float* s2 = (float*)sm;
        for (int i = t; i < 4096; i += 256) { float v = style[i]; s2[i] = v * v; }
        __syncthreads();
        const float4* wp = (const float4*)(weight + (size_t)co * 4608);
        float acc[8] = {0.f, 0.f, 0.f, 0.f, 0.f, 0.f, 0.f, 0.f};
        for (int j = t; j < 1152; j += 256) {
            float4 v = wp[j];
            float w2[4] = {v.x * v.x, v.y * v.y, v.z * v.z, v.w * v.w};
            int base = j * 4;
#pragma unroll
            for (int e = 0; e < 4; ++e) {
                int ci = (base + e) / 9;
                float ww = w2[e];
#pragma unroll
                for (int bb = 0; bb < 8; ++bb) acc[bb] += ww * s2[bb * 512 + ci];
            }
        }
#pragma unroll
        for (int bb = 0; bb < 8; ++bb)
            for (int off = 32; off > 0; off >>= 1)
                acc[bb] += __shfl_down(acc[bb], off);
        float* red = (float*)(sm + 16384);
        const int wv = t >> 6, lane = t & 63;
        if (lane == 0) {
#pragma unroll
            for (int bb = 0; bb < 8; ++bb) red[wv * 8 + bb] = acc[bb];
        }
        __syncthreads();
        if (t < 8) {
            float s = red[t] + red[8 + t] + red[16 + t] + red[24 + t];
            const float S2 = MOD_SCALE * MOD_SCALE;
            dem[t * 512 + co] = rsqrtf(S2 * s + 1e-8f);
        }
    }
}

// ---------------------------------------------------------------------------
// Conv: EXACT R12 body — the measured record (251.18 us total, k_conv 133.6).
// Implicit GEMM, 32x32x16 MFMA, block 128co x 256sp, 4 waves (wm = co half,
// wn = row pair), wave tile 64co x 128sp (2x4 frags). W in LDS, 2 banks x 3
// taps, prefetched one 3-tap phase ahead (full-phase slack -> free drain);
// X single buffer restaged at cb end between its own barrier pair. Rotation
// swizzle: LDS slot s of entry e holds global chunk (s-(e>>2))&3; readers
// use slot (c+(e>>2))&3 -> 0 bank conflicts measured. Blocked-xs cb stride
// 278,784 B. LDS 74,496 B -> exactly 2 blocks/CU at grid 512.
// Terminal config: six structural variants (R7/R9/R10/R14/R15/R17) bracket
// this at 133-192 us; none beat it.
// ---------------------------------------------------------------------------
__global__ __launch_bounds__(256, 2) void k_conv(
    const __hip_bfloat16* __restrict__ xs,   // [b][16][66][66][64B] blocked
    const __hip_bfloat16* __restrict__ wb,   // [9][512][512] tap-major
    const float* __restrict__ demod,
    const float* __restrict__ noise,
    const float* __restrict__ bias,
    const float* __restrict__ nstr,
    float* __restrict__ out) {
    __shared__ __align__(16) char Xl[25344];     // 396 entries x 64 B
    __shared__ __align__(16) char Wl[6][8192];   // 2 banks x 3 taps x 8 KB

    const int t = threadIdx.x;
    const int bi = blockIdx.x;
    const int spat = bi & 127;            // same spat -> same bi%8 -> same XCD
    const int b = spat >> 4;
    const int h0 = (spat & 15) << 2;
    const int co0 = (bi >> 7) << 7;
    const int lane = t & 63;
    const int wv = t >> 6;
    const int wm = wv & 1, wn = wv >> 1;
    const int el = lane & 31;
    const int hk = lane >> 5;

    f32x16 acc[2][4];
#pragma unroll
    for (int i = 0; i < 2; ++i)
#pragma unroll
        for (int j = 0; j < 4; ++j)
#pragma unroll
            for (int k = 0; k < 16; ++k) acc[i][j][k] = 0.f;

    // ---- staging source pointers (rotation-swizzled) ----
    const char* xsb = (const char*)xs + (size_t)b * 4460544;
    const char* xsrc[7];
#pragma unroll
    for (int i = 0; i < 6; ++i) {
        int g = i * 256 + t;
        int e = g >> 2, s = g & 3;
        int gc = (s - (e >> 2)) & 3;
        int row = e / 66, col = e - row * 66;
        xsrc[i] = xsb + (size_t)((h0 + row) * 66 + col) * 64 + gc * 16;
    }
    {   // tail entries 384..395 (threads 0..47 only)
        int g = 1536 + t;
        int e = g >> 2, s = g & 3;
        int gc = (s - (e >> 2)) & 3;
        int row = e / 66, col = e - row * 66;
        xsrc[6] = xsb + (size_t)((h0 + row) * 66 + col) * 64 + gc * 16;
    }
    const char* wsrc[2];
#pragma unroll
    for (int i = 0; i < 2; ++i) {
        int g = i * 256 + t;
        int e = g >> 2, s = g & 3;
        int gc = (s - (e >> 2)) & 3;
        wsrc[i] = (const char*)wb + (size_t)(co0 + e) * 1024 + gc * 16;
    }
    const int wvoff = wv << 10;

    // ---- prologue: X(cb=0) + W phase 0 (taps 0-2 -> buffers 0-2) ----
#pragma unroll
    for (int i = 0; i < 6; ++i) gload_lds16(xsrc[i], Xl + i * 4096 + wvoff);
    if (t < 48) gload_lds16(xsrc[6], Xl + 24576);
#pragma unroll
    for (int tt = 0; tt < 3; ++tt)
#pragma unroll
        for (int i = 0; i < 2; ++i)
            gload_lds16(wsrc[i] + (size_t)tt * 524288,
                        Wl[tt] + i * 4096 + wvoff);
    sync_drain();

    int cboff = 0;
    for (int cb = 0; cb < 16; ++cb, cboff += 64) {
        const int ncboff = (cb < 15) ? cboff + 64 : cboff;  // cb15: dead dummy
#pragma unroll
        for (int p = 0; p < 3; ++p) {
            const int bank = ((cb + p) & 1) * 3;
            const int nbank = 3 - bank;
            // ---- prefetch phase p+1 (6 loads/wave) into the other bank ----
#pragma unroll
            for (int tt = 0; tt < 3; ++tt) {
                const size_t soff = (p < 2)
                    ? (size_t)(3 * (p + 1) + tt) * 524288 + cboff
                    : (size_t)tt * 524288 + ncboff;
                char* dst = Wl[nbank + tt] + wvoff;
#pragma unroll
                for (int i = 0; i < 2; ++i)
                    gload_lds16(wsrc[i] + soff, dst + i * 4096);
            }
            // ---- compute taps 3p..3p+2 (dh = p, dw = tt), barrier-free ----
#pragma unroll
            for (int tt = 0; tt < 3; ++tt) {
                const char* Wb = Wl[bank + tt];
#pragma unroll
                for (int ks = 0; ks < 2; ++ks) {
                    const int c = 2 * ks + hk;
                    s16x8 af[2], bfr[4];
#pragma unroll
                    for (int mi = 0; mi < 2; ++mi) {
                        int e = wm * 64 + mi * 32 + el;
                        af[mi] = *(const s16x8*)(Wb + e * 64 +
                                                 (((c + (e >> 2)) & 3) << 4));
                    }
#pragma unroll
                    for (int ni = 0; ni < 4; ++ni) {
                        int e = (2 * wn + (ni >> 1) + p) * 66 + tt +
                                (ni & 1) * 32 + el;
                        bfr[ni] = *(const s16x8*)(Xl + e * 64 +
                                                  (((c + (e >> 2)) & 3) << 4));
                    }
#pragma unroll
                    for (int mi = 0; mi < 2; ++mi)
#pragma unroll
                        for (int ni = 0; ni < 4; ++ni)
                            acc[mi][ni] =
                                __builtin_amdgcn_mfma_f32_32x32x16_bf16(
                                    af[mi], bfr[ni], acc[mi][ni], 0, 0, 0);
                }
            }
            // ---- phase barrier: drains phase p+1 loads (full-phase slack) ----
            sync_drain();
        }
        // ---- restage X (single buffer, between its own barrier pair) ----
        if (cb < 15) {
            const size_t xo = (size_t)(cb + 1) * 278784;
#pragma unroll
            for (int i = 0; i < 6; ++i)
                gload_lds16(xsrc[i] + xo, Xl + i * 4096 + wvoff);
            if (t < 48) gload_lds16(xsrc[6] + xo, Xl + 24576);
            sync_drain();
        }
    }

    // ---- epilogue: *demod + noise*strength + bias, leaky_relu(0.2)*sqrt(2) ----
    const float nsv = nstr[0];
    const float LR = 1.4142135623730951f;
#pragma unroll
    for (int mi = 0; mi < 2; ++mi) {
        float dm[16], bs[16];
#pragma unroll
        for (int rg = 0; rg < 16; ++rg) {
            int co = co0 + wm * 64 + mi * 32 + (rg & 3) + 8 * (rg >> 2) + 4 * hk;
            dm[rg] = demod[b * 512 + co];
            bs[rg] = bias[co];
        }
#pragma unroll
        for (int ni = 0; ni < 4; ++ni) {
            int h = h0 + 2 * wn + (ni >> 1);
            int w = (ni & 1) * 32 + el;
            float nz = nsv * noise[h * 64 + w];
#pragma unroll
            for (int rg = 0; rg < 16; ++rg) {
                int co = co0 + wm * 64 + mi * 32 + (rg & 3) + 8 * (rg >> 2) +
                         4 * hk;
                float v = acc[mi][ni][rg] * dm[rg] + nz + bs[rg];
                v = (v >= 0.f ? v : 0.2f * v) * LR;
                out[(((size_t)b * 512 + co) * 64 + h) * 64 + w] = v;
            }
        }
    }
}

// ---------------------------------------------------------------------------
extern "C" void kernel_launch(void* const* d_in, const int* in_sizes, int n_in,
                              void* d_out, int out_size, void* d_ws, size_t ws_size,
                              hipStream_t stream) {
    const float* x      = (const float*)d_in[0];
    const float* style  = (const float*)d_in[1];
    const float* noise  = (const float*)d_in[2];
    const float* weight = (const float*)d_in[3];
    const float* bias   = (const float*)d_in[4];
    const float* nstr   = (const float*)d_in[5];
    float* out = (float*)d_out;

    char* ws = (char*)d_ws;
    __hip_bfloat16* xs = (__hip_bfloat16*)ws;              // 35,684,352 B (blocked)
    __hip_bfloat16* wb = (__hip_bfloat16*)(ws + 35684352); //  4,718,592 B
    float* demod = (float*)(ws + 35684352 + 4718592);      //     16,384 B

    k_prep<<<2568, 256, 0, stream>>>(x, style, weight, xs, wb, demod);
    k_conv<<<512, 256, 0, stream>>>(xs, wb, demod, noise, bias, nstr, out);
}